// Round 7
// baseline (287.986 us; speedup 1.0000x reference)
//
#include <hip/hip_runtime.h>

#define TT 128
#define BB 512
#define DD 500
#define NVOCAB 1000
#define NV4 125   // DD floats = 125 float4 per row (2000 B, 16B-aligned)

// ---------------------------------------------------------------------------
// Workspace layout (ws 16B-aligned), 140 KB:
//   mask    : ulonglong2[BB]   (128-bit valid mask per column)        8 KB
//   lohi    : ushort[TT*BB]    (lo | hi<<7 per segment)             128 KB
//   inv     : int[BB]          (column b -> sorted output slot j)     2 KB
//   nlen    : int[BB]          (column b -> its segment count n)      2 KB
// ---------------------------------------------------------------------------

// Kernel 1: fused metadata + sort. ONE block, 512 threads (1 thread/column).
// Same as rounds 4-6 (passed all), now also emitting the inverse permutation
// inv[b] (= rank of column b) and per-column nlen[b] for the streaming gather.
__global__ void __launch_bounds__(512)
meta_sort_kernel(const int* __restrict__ src,
                 const int* __restrict__ token_lengths,
                 const int* __restrict__ token_len_p,
                 unsigned short* __restrict__ lohi,
                 ulonglong2* __restrict__ mask,
                 int* __restrict__ inv,
                 int* __restrict__ nlen,
                 float* __restrict__ out_len) {
    __shared__ int tl[NVOCAB];
    __shared__ int lens[BB];
    __shared__ int sord[BB];
    int b = threadIdx.x;
    for (int i = b; i < NVOCAB; i += 512) tl[i] = token_lengths[i];
    __syncthreads();

    // token_len arrives as a 1-element int array; guard vs f32 bits.
    int bits = token_len_p[0];
    int token_len = bits;
    if (bits > 1000000 || bits <= 0) token_len = (int)__int_as_float(bits);

    int curr = 0, seg = 0, lo = 0, pend = -1;
    unsigned long long m0 = 0ull, m1 = 0ull;
    for (int t0 = 0; t0 < TT; t0 += 16) {
        int s_arr[16];
        #pragma unroll
        for (int k = 0; k < 16; ++k) s_arr[k] = src[(t0 + k) * BB + b];
        #pragma unroll
        for (int k = 0; k < 16; ++k) {
            int t = t0 + k;
            int s = s_arr[k];
            if (s == 1) continue;              // pad: invalid
            int l = (s == 0) ? 4 : tl[s];
            if (pend >= 0 && curr + l > token_len) {
                lohi[seg * BB + b] = (unsigned short)(lo | (pend << 7));
                lo = pend + 1; curr = 0; seg++;
            }
            curr += l; pend = t;
            if (t < 64) m0 |= 1ull << t; else m1 |= 1ull << (t - 64);
        }
    }
    if (pend >= 0) {                           // final segment (nxt==BIG)
        lohi[seg * BB + b] = (unsigned short)(lo | (pend << 7));
        seg++;
    }
    mask[b] = make_ulonglong2(m0, m1);
    lens[b] = seg;
    nlen[b] = seg;
    __syncthreads();

    // stable descending rank-count sort (thread b doubles as output slot j)
    int lj = lens[b];
    int rank = 0;
    #pragma unroll 8
    for (int i = 0; i < BB; ++i) {
        int li = lens[i];
        rank += (int)((li > lj) || (li == lj && i < b));
    }
    inv[b] = rank;                             // column b lands at slot rank
    sord[rank] = b;
    __syncthreads();
    out_len[b] = (float)lens[sord[b]];         // thread b doubles as slot j
}

// ---------------------------------------------------------------------------
// Kernel 2: SINGLE-PASS column-streaming gather. One block (128 threads) per
// column b: stream t = 0..127 ascending (each 2000 B row chunk read EXACTLY
// once), accumulate with 0/1 weights, emit out[s][j] at each segment's hi,
// and emit out[t][j] = raw row whenever t >= n (identity rows).
//   - serviced reads drop 228 MB -> 131 MB (identity re-read eliminated);
//   - 512 blocks advancing t in rough lockstep collectively read dense 1 MB
//     rows of emb -> streaming HBM read pattern;
//   - batch-8, 2-deep pipelined prefetch pinned with sched_barrier(0)
//     (round-5-proven: the only form hipcc doesn't re-serialize).
// Accumulation is ascending-t with exact 0.0/1.0 weights => bit-exact.
// ---------------------------------------------------------------------------
__global__ void __launch_bounds__(128)
stream_kernel(const float* __restrict__ emb,
              const int* __restrict__ inv,
              const int* __restrict__ nlen,
              const unsigned short* __restrict__ lohi,
              const ulonglong2* __restrict__ mask,
              float* __restrict__ out) {
    int b   = blockIdx.x;
    int tid = threadIdx.x;                       // 0..127, lanes 0..124 active
    __shared__ unsigned char sh_hi[TT + 1];      // hi per segment, 255 sentinel

    int n = nlen[b];                             // uniform scalar loads
    int j = inv[b];
    ulonglong2 m = mask[b];

    if (tid <= TT) sh_hi[tid] = 255;
    __syncthreads();
    if (tid < n) {
        int lh = (int)lohi[tid * BB + b];
        sh_hi[tid] = (unsigned char)((lh >> 7) & 127);
    }
    __syncthreads();

    bool act = tid < NV4;
    int  dc  = act ? tid : 0;                    // clamped float4 lane index
    const float4* e4 = (const float4*)emb;
    float4*       o4 = (float4*)out;

    float4 acc = make_float4(0.f, 0.f, 0.f, 0.f);
    int seg = 0;
    float4 xa[8], xb[8];

#define ISSUE(buf, t0)                                                        \
    _Pragma("unroll")                                                         \
    for (int k = 0; k < 8; ++k)                                               \
        buf[k] = e4[((size_t)(((t0) + k) * BB + b)) * NV4 + dc];

#define CONSUME(buf, t0)                                                      \
    _Pragma("unroll")                                                         \
    for (int k = 0; k < 8; ++k) {                                             \
        int t = (t0) + k;                                                     \
        float4 x = buf[k];                                                    \
        float w = (float)((((t < 64) ? (m.x >> t) : (m.y >> (t - 64)))) & 1ull); \
        acc.x = fmaf(w, x.x, acc.x); acc.y = fmaf(w, x.y, acc.y);             \
        acc.z = fmaf(w, x.z, acc.z); acc.w = fmaf(w, x.w, acc.w);             \
        if (t == (int)sh_hi[seg]) {              /* uniform branch */         \
            if (act) o4[((size_t)(seg * BB + j)) * NV4 + tid] = acc;          \
            acc = make_float4(0.f, 0.f, 0.f, 0.f);                            \
            seg++;                                                            \
        }                                                                     \
        if (t >= n && act)                       /* identity row */           \
            o4[((size_t)(t * BB + j)) * NV4 + tid] = x;                       \
    }

    ISSUE(xa, 0);
    __builtin_amdgcn_sched_barrier(0);
    for (int t0 = 0; t0 < TT; t0 += 16) {
        ISSUE(xb, t0 + 8);
        __builtin_amdgcn_sched_barrier(0);
        CONSUME(xa, t0);
        if (t0 + 16 < TT) {
            ISSUE(xa, t0 + 16);
        }
        __builtin_amdgcn_sched_barrier(0);
        CONSUME(xb, t0 + 8);
    }
#undef ISSUE
#undef CONSUME
}

extern "C" void kernel_launch(void* const* d_in, const int* in_sizes, int n_in,
                              void* d_out, int out_size, void* d_ws, size_t ws_size,
                              hipStream_t stream) {
    const float* embedded      = (const float*)d_in[0];
    const int*   src           = (const int*)d_in[1];
    // d_in[2] = lengths (unused by reference computation)
    const int*   token_lengths = (const int*)d_in[3];
    const int*   token_len_p   = (const int*)d_in[4];

    float* out = (float*)d_out;                 // T*B*D packed rows + B lengths

    ulonglong2*     mask = (ulonglong2*)d_ws;                       // 8 KB
    unsigned short* lohi = (unsigned short*)(mask + BB);            // 128 KB
    int*            inv  = (int*)(lohi + TT * BB);                  // 2 KB
    int*            nlen = inv + BB;                                // 2 KB

    meta_sort_kernel<<<1, BB, 0, stream>>>(src, token_lengths, token_len_p,
                                           lohi, mask, inv, nlen,
                                           out + (size_t)TT * BB * DD);
    stream_kernel<<<BB, 128, 0, stream>>>(embedded, inv, nlen, lohi, mask, out);
}